// Round 3
// baseline (827.947 us; speedup 1.0000x reference)
//
#include <hip/hip_runtime.h>
#include <hip/hip_bf16.h>

// Segment enumeration: degrees 8,7,6,5,4 — each segment is 4096 contiguous
// floats of one polynomial row (16 KB). counts: 8*4096, 8*512, 8*64, 8*8, 8*1.
#define OFF7 32768
#define OFF6 36864
#define OFF5 37376
#define OFF4 37440
#define NSEG 37448

typedef float f4v __attribute__((ext_vector_type(4)));

__device__ __forceinline__ float4 ldnt(const float* p) {
    f4v v = __builtin_nontemporal_load((const f4v*)p);
    return make_float4(v.x, v.y, v.z, v.w);
}
__device__ __forceinline__ float4 mul4(float4 a, float4 b) {
    return make_float4(a.x * b.x, a.y * b.y, a.z * b.z, a.w * b.w);
}
__device__ __forceinline__ float4 fma4s(float s, float4 b, float4 c) {
    return make_float4(fmaf(s, b.x, c.x), fmaf(s, b.y, c.y),
                       fmaf(s, b.z, c.z), fmaf(s, b.w, c.w));
}
__device__ __forceinline__ float4 fma44(float4 a, float4 b, float4 c) {
    return make_float4(fmaf(a.x, b.x, c.x), fmaf(a.y, b.y, c.y),
                       fmaf(a.z, b.z, c.z), fmaf(a.w, b.w, c.w));
}

// Degrees 4..8. Identity: for element m = k*256 + l*4 + j of a 4096-float
// segment, kron^4[m] = T2[k*4 + (l>>4)] * T2[(l&15)*4 + j]. Low factor fixed
// per lane (registers), high factor is a broadcast LDS read.
// Each wave owns a CONTIGUOUS run of segments [w*NSEG/W, (w+1)*NSEG/W) and
// software-pipelines half-segment (8 x float4) chunks across segments so
// ~8KB/wave stays in flight during compute. Cross-segment register
// accumulation (runacc), flushed only on polynomial-index change.
__global__ __launch_bounds__(512, 4) void poly_big(
    const float* __restrict__ X,
    const float* __restrict__ c4, const float* __restrict__ c5,
    const float* __restrict__ c6, const float* __restrict__ c7,
    const float* __restrict__ c8, float* __restrict__ ws)
{
    __shared__ float4 T1s[8], T2s[64];
    __shared__ float part[32];
    const int tid = threadIdx.x;

    if (tid < 8)  T1s[tid] = make_float4(X[tid], X[8 + tid], X[16 + tid], X[24 + tid]);
    if (tid < 32) part[tid] = 0.f;
    __syncthreads();
    if (tid < 64) T2s[tid] = mul4(T1s[tid >> 3], T1s[tid & 7]);
    __syncthreads();

    const int l = tid & 63;
    const int lhi = l >> 4;
    const float4 tl0 = T2s[((l & 15) << 2) + 0];
    const float4 tl1 = T2s[((l & 15) << 2) + 1];
    const float4 tl2 = T2s[((l & 15) << 2) + 2];
    const float4 tl3 = T2s[((l & 15) << 2) + 3];

    const int w = (blockIdx.x * blockDim.x + tid) >> 6;
    const int W = (gridDim.x * blockDim.x) >> 6;
    int g    = (int)(((long long)w * NSEG) / W);
    int gend = (int)(((long long)(w + 1) * NSEG) / W);

    // decode: segment g -> lane base pointer, polynomial p, per-segment factor
    auto decode = [&](int gg, const float*& srcl, int& p, float4& th) {
        const float* src; int hi;
        if (gg < OFF7) {
            p = gg >> 12; hi = gg & 4095; src = c8 + ((size_t)p << 24);
            th = mul4(T2s[hi >> 6], T2s[hi & 63]);
        } else if (gg < OFF6) {
            int s = gg - OFF7; p = s >> 9; hi = s & 511; src = c7 + ((size_t)p << 21);
            th = mul4(T1s[hi >> 6], T2s[hi & 63]);
        } else if (gg < OFF5) {
            int s = gg - OFF6; p = s >> 6; hi = s & 63; src = c6 + ((size_t)p << 18);
            th = T2s[hi];
        } else if (gg < OFF4) {
            int s = gg - OFF5; p = s >> 3; hi = s & 7; src = c5 + ((size_t)p << 15);
            th = T1s[hi];
        } else {
            int s = gg - OFF4; p = s; hi = 0; src = c4 + ((size_t)p << 12);
            th = make_float4(1.f, 1.f, 1.f, 1.f);
        }
        srcl = src + ((size_t)hi << 12) + (l << 2);
    };

    const float* srcl; int curp; float4 thseg;
    decode(g, srcl, curp, thseg);
    float4 A[8], B[8];
    #pragma unroll
    for (int k = 0; k < 8; ++k) A[k] = ldnt(srcl + (k << 8));
    #pragma unroll
    for (int k = 0; k < 8; ++k) B[k] = ldnt(srcl + ((k + 8) << 8));
    float4 runacc = make_float4(0.f, 0.f, 0.f, 0.f);

    while (g < gend) {
        float4 acc = make_float4(0.f, 0.f, 0.f, 0.f);
        #pragma unroll
        for (int k = 0; k < 8; ++k) {
            const float4 cv = A[k];
            const float4 th = T2s[(k << 2) + lhi];
            float4 inner = make_float4(cv.x * tl0.x, cv.x * tl0.y,
                                       cv.x * tl0.z, cv.x * tl0.w);
            inner = fma4s(cv.y, tl1, inner);
            inner = fma4s(cv.z, tl2, inner);
            inner = fma4s(cv.w, tl3, inner);
            acc = fma44(th, inner, acc);
        }
        const bool more = (g + 1 < gend);
        const float* nsrcl = srcl; int np = curp; float4 nth = thseg;
        if (more) {
            decode(g + 1, nsrcl, np, nth);
            #pragma unroll
            for (int k = 0; k < 8; ++k) A[k] = ldnt(nsrcl + (k << 8));
        }
        #pragma unroll
        for (int k = 8; k < 16; ++k) {
            const float4 cv = B[k - 8];
            const float4 th = T2s[(k << 2) + lhi];
            float4 inner = make_float4(cv.x * tl0.x, cv.x * tl0.y,
                                       cv.x * tl0.z, cv.x * tl0.w);
            inner = fma4s(cv.y, tl1, inner);
            inner = fma4s(cv.z, tl2, inner);
            inner = fma4s(cv.w, tl3, inner);
            acc = fma44(th, inner, acc);
        }
        if (more) {
            #pragma unroll
            for (int k = 0; k < 8; ++k) B[k] = ldnt(nsrcl + ((k + 8) << 8));
        }
        runacc = fma44(acc, thseg, runacc);

        if (!more || np != curp) {
            float vx = runacc.x, vy = runacc.y, vz = runacc.z, vw = runacc.w;
            #pragma unroll
            for (int m = 32; m; m >>= 1) {
                vx += __shfl_xor(vx, m);
                vy += __shfl_xor(vy, m);
                vz += __shfl_xor(vz, m);
                vw += __shfl_xor(vw, m);
            }
            if (l == 0) {
                atomicAdd(&part[(curp << 2) + 0], vx);
                atomicAdd(&part[(curp << 2) + 1], vy);
                atomicAdd(&part[(curp << 2) + 2], vz);
                atomicAdd(&part[(curp << 2) + 3], vw);
            }
            runacc = make_float4(0.f, 0.f, 0.f, 0.f);
        }
        srcl = nsrcl; curp = np; thseg = nth;
        ++g;
    }
    __syncthreads();
    // ws layout: [block][o] with o = neu*8 + p  (matches output layout)
    if (tid < 32) ws[(size_t)blockIdx.x * 32 + tid] = part[((tid & 7) << 2) + (tid >> 3)];
}

// Finalize: reduce block partials + bias + degrees 1..3.
__global__ __launch_bounds__(256) void poly_final(
    const float* __restrict__ X, const float* __restrict__ bias,
    const float* __restrict__ c1, const float* __restrict__ c2,
    const float* __restrict__ c3, const float* __restrict__ ws,
    int nblocks, float* __restrict__ out)
{
    __shared__ float xs[4][8];
    __shared__ float redA[8][32];
    __shared__ float redB[8][32][4];
    const int t = threadIdx.x;
    if (t < 32) xs[t >> 3][t & 7] = X[t];
    __syncthreads();

    // Phase A: sum the big-kernel partials. o = neu*8+p, 8 groups stride blocks.
    {
        int o = t & 31, grp = t >> 5;
        float s = 0.f;
        for (int b = grp; b < nblocks; b += 8) s += ws[(size_t)b * 32 + o];
        redA[grp][o] = s;
    }
    // Phase B: degrees 1..3. p = t>>5, 32 lanes per polynomial.
    {
        int p = t >> 5, li = t & 31;
        float s0 = 0.f, s1 = 0.f, s2 = 0.f, s3 = 0.f;
        for (int i = li; i < 512; i += 32) {
            float cv = c3[(p << 9) + i];
            int d1 = (i >> 6) & 7, d2 = (i >> 3) & 7, d3 = i & 7;
            s0 = fmaf(cv, xs[0][d1] * xs[0][d2] * xs[0][d3], s0);
            s1 = fmaf(cv, xs[1][d1] * xs[1][d2] * xs[1][d3], s1);
            s2 = fmaf(cv, xs[2][d1] * xs[2][d2] * xs[2][d3], s2);
            s3 = fmaf(cv, xs[3][d1] * xs[3][d2] * xs[3][d3], s3);
        }
        for (int i = li; i < 64; i += 32) {
            float cv = c2[(p << 6) + i];
            int d1 = (i >> 3) & 7, d2 = i & 7;
            s0 = fmaf(cv, xs[0][d1] * xs[0][d2], s0);
            s1 = fmaf(cv, xs[1][d1] * xs[1][d2], s1);
            s2 = fmaf(cv, xs[2][d1] * xs[2][d2], s2);
            s3 = fmaf(cv, xs[3][d1] * xs[3][d2], s3);
        }
        if (li < 8) {
            float cv = c1[(p << 3) + li];
            s0 = fmaf(cv, xs[0][li], s0);
            s1 = fmaf(cv, xs[1][li], s1);
            s2 = fmaf(cv, xs[2][li], s2);
            s3 = fmaf(cv, xs[3][li], s3);
        }
        redB[p][li][0] = s0; redB[p][li][1] = s1; redB[p][li][2] = s2; redB[p][li][3] = s3;
    }
    __syncthreads();
    if (t < 32) {
        int neu = t >> 3, p = t & 7;
        float tot = bias[p];
        #pragma unroll
        for (int grp = 0; grp < 8; ++grp) tot += redA[grp][t];
        for (int li = 0; li < 32; ++li) tot += redB[p][li][neu];
        out[t] = tot;
    }
}

extern "C" void kernel_launch(void* const* d_in, const int* in_sizes, int n_in,
                              void* d_out, int out_size, void* d_ws, size_t ws_size,
                              hipStream_t stream) {
    const float* X    = (const float*)d_in[0];
    const float* bias = (const float*)d_in[1];
    const float* c1   = (const float*)d_in[2];
    const float* c2   = (const float*)d_in[3];
    const float* c3   = (const float*)d_in[4];
    const float* c4   = (const float*)d_in[5];
    const float* c5   = (const float*)d_in[6];
    const float* c6   = (const float*)d_in[7];
    const float* c7   = (const float*)d_in[8];
    const float* c8   = (const float*)d_in[9];
    float* out = (float*)d_out;
    float* ws  = (float*)d_ws;

    int blocks = 512;
    size_t maxb = ws_size / (32 * sizeof(float));
    if ((size_t)blocks > maxb) blocks = (int)maxb;
    if (blocks < 1) blocks = 1;

    poly_big<<<blocks, 512, 0, stream>>>(X, c4, c5, c6, c7, c8, ws);
    poly_final<<<1, 256, 0, stream>>>(X, bias, c1, c2, c3, ws, blocks, out);
}

// Round 4
// 399.318 us; speedup vs baseline: 2.0734x; 2.0734x over previous
//
#include <hip/hip_runtime.h>
#include <hip/hip_bf16.h>

// Segment enumeration: degrees 8,7,6,5,4 — each segment is 4096 contiguous
// floats of one polynomial row (16 KB). counts: 8*4096, 8*512, 8*64, 8*8, 8*1.
#define OFF7 32768
#define OFF6 36864
#define OFF5 37376
#define OFF4 37440
#define NSEG 37448

__device__ __forceinline__ float4 mul4(float4 a, float4 b) {
    return make_float4(a.x * b.x, a.y * b.y, a.z * b.z, a.w * b.w);
}
__device__ __forceinline__ float4 fma4s(float s, float4 b, float4 c) {
    return make_float4(fmaf(s, b.x, c.x), fmaf(s, b.y, c.y),
                       fmaf(s, b.z, c.z), fmaf(s, b.w, c.w));
}
__device__ __forceinline__ float4 fma44(float4 a, float4 b, float4 c) {
    return make_float4(fmaf(a.x, b.x, c.x), fmaf(a.y, b.y, c.y),
                       fmaf(a.z, b.z, c.z), fmaf(a.w, b.w, c.w));
}

struct SegInfo {
    const float4* base;  // per-lane pointer into the segment
    float4 th;           // per-segment high Kronecker factor (4 neurons)
    int p;               // polynomial row 0..7
};

// Plain by-value decode: no references, no lambda — keeps SROA trivial.
__device__ __forceinline__ SegInfo seg_decode(
    int g, int l,
    const float* c4, const float* c5, const float* c6,
    const float* c7, const float* c8,
    const float4* T1s, const float4* T2s)
{
    SegInfo si;
    const float* s;
    if (g < OFF7) {
        si.p = g >> 12; int hi = g & 4095;
        s = c8 + ((size_t)si.p << 24) + ((size_t)hi << 12);
        si.th = mul4(T2s[hi >> 6], T2s[hi & 63]);
    } else if (g < OFF6) {
        int t = g - OFF7; si.p = t >> 9; int hi = t & 511;
        s = c7 + ((size_t)si.p << 21) + ((size_t)hi << 12);
        si.th = mul4(T1s[hi >> 6], T2s[hi & 63]);
    } else if (g < OFF5) {
        int t = g - OFF6; si.p = t >> 6; int hi = t & 63;
        s = c6 + ((size_t)si.p << 18) + ((size_t)hi << 12);
        si.th = T2s[hi];
    } else if (g < OFF4) {
        int t = g - OFF5; si.p = t >> 3; int hi = t & 7;
        s = c5 + ((size_t)si.p << 15) + ((size_t)hi << 12);
        si.th = T1s[hi];
    } else {
        si.p = g - OFF4;
        s = c4 + ((size_t)si.p << 12);
        si.th = make_float4(1.f, 1.f, 1.f, 1.f);
    }
    si.base = (const float4*)s + l;
    return si;
}

// chunk k of a segment lives at base + k*64 float4s (1 KB per chunk per wave)
#define LOADA(si) { A0 = (si).base[0];   A1 = (si).base[64];  A2 = (si).base[128]; A3 = (si).base[192]; \
                    A4 = (si).base[256]; A5 = (si).base[320]; A6 = (si).base[384]; A7 = (si).base[448]; }
#define LOADB(si) { B0 = (si).base[512]; B1 = (si).base[576]; B2 = (si).base[640]; B3 = (si).base[704]; \
                    B4 = (si).base[768]; B5 = (si).base[832]; B6 = (si).base[896]; B7 = (si).base[960]; }
// one 64-float4 chunk: acc += T2[k*4+lhi] * (cv.x*tl0 + cv.y*tl1 + cv.z*tl2 + cv.w*tl3)
#define STEP(cv, kk) { const float4 th_ = T2s[((kk) << 2) + lhi]; \
    float4 inner = make_float4((cv).x * tl0.x, (cv).x * tl0.y, (cv).x * tl0.z, (cv).x * tl0.w); \
    inner = fma4s((cv).y, tl1, inner); \
    inner = fma4s((cv).z, tl2, inner); \
    inner = fma4s((cv).w, tl3, inner); \
    acc = fma44(th_, inner, acc); }

// Degrees 4..8. Identity: for element m = k*256 + l*4 + j of a 4096-float
// segment, kron^4[m] = T2[k*4 + (l>>4)] * T2[(l&15)*4 + j]. Low factor fixed
// per lane (registers), high factor is a broadcast LDS read. Grid-stride
// over segments; while computing segment g, the 16 loads of segment g+W are
// issued into the just-freed named registers (A half, then B half).
__global__ __launch_bounds__(512, 4) void poly_big(
    const float* __restrict__ X,
    const float* __restrict__ c4, const float* __restrict__ c5,
    const float* __restrict__ c6, const float* __restrict__ c7,
    const float* __restrict__ c8, float* __restrict__ ws)
{
    __shared__ float4 T1s[8], T2s[64];
    __shared__ float part[32];
    const int tid = threadIdx.x;

    if (tid < 8)  T1s[tid] = make_float4(X[tid], X[8 + tid], X[16 + tid], X[24 + tid]);
    if (tid < 32) part[tid] = 0.f;
    __syncthreads();
    if (tid < 64) T2s[tid] = mul4(T1s[tid >> 3], T1s[tid & 7]);
    __syncthreads();

    const int l = tid & 63;
    const int lhi = l >> 4;
    const float4 tl0 = T2s[((l & 15) << 2) + 0];
    const float4 tl1 = T2s[((l & 15) << 2) + 1];
    const float4 tl2 = T2s[((l & 15) << 2) + 2];
    const float4 tl3 = T2s[((l & 15) << 2) + 3];

    const int wid = (blockIdx.x * blockDim.x + tid) >> 6;
    const int W   = (gridDim.x * blockDim.x) >> 6;

    if (wid < NSEG) {
        SegInfo cur = seg_decode(wid, l, c4, c5, c6, c7, c8, T1s, T2s);
        float4 A0, A1, A2, A3, A4, A5, A6, A7;
        float4 B0, B1, B2, B3, B4, B5, B6, B7;
        LOADA(cur);
        LOADB(cur);

        for (int g = wid; g < NSEG; ) {
            const int gn = g + W;          // wave-uniform
            float4 acc = make_float4(0.f, 0.f, 0.f, 0.f);
            STEP(A0, 0) STEP(A1, 1) STEP(A2, 2) STEP(A3, 3)
            STEP(A4, 4) STEP(A5, 5) STEP(A6, 6) STEP(A7, 7)
            SegInfo nxt = cur;
            if (gn < NSEG) {
                nxt = seg_decode(gn, l, c4, c5, c6, c7, c8, T1s, T2s);
                LOADA(nxt);
            }
            STEP(B0, 8)  STEP(B1, 9)  STEP(B2, 10) STEP(B3, 11)
            STEP(B4, 12) STEP(B5, 13) STEP(B6, 14) STEP(B7, 15)
            if (gn < NSEG) {
                LOADB(nxt);
            }

            float vx = acc.x * cur.th.x, vy = acc.y * cur.th.y,
                  vz = acc.z * cur.th.z, vw = acc.w * cur.th.w;
            #pragma unroll
            for (int m = 32; m; m >>= 1) {
                vx += __shfl_xor(vx, m);
                vy += __shfl_xor(vy, m);
                vz += __shfl_xor(vz, m);
                vw += __shfl_xor(vw, m);
            }
            if (l == 0) {
                atomicAdd(&part[(cur.p << 2) + 0], vx);
                atomicAdd(&part[(cur.p << 2) + 1], vy);
                atomicAdd(&part[(cur.p << 2) + 2], vz);
                atomicAdd(&part[(cur.p << 2) + 3], vw);
            }
            cur = nxt;
            g = gn;
        }
    }
    __syncthreads();
    // ws layout: [block][o] with o = neu*8 + p  (matches output layout)
    if (tid < 32) ws[(size_t)blockIdx.x * 32 + tid] = part[((tid & 7) << 2) + (tid >> 3)];
}

// Finalize: reduce block partials + bias + degrees 1..3.
__global__ __launch_bounds__(256) void poly_final(
    const float* __restrict__ X, const float* __restrict__ bias,
    const float* __restrict__ c1, const float* __restrict__ c2,
    const float* __restrict__ c3, const float* __restrict__ ws,
    int nblocks, float* __restrict__ out)
{
    __shared__ float xs[4][8];
    __shared__ float redA[8][32];
    __shared__ float redB[8][32][4];
    const int t = threadIdx.x;
    if (t < 32) xs[t >> 3][t & 7] = X[t];
    __syncthreads();

    // Phase A: sum the big-kernel partials. o = neu*8+p, 8 groups stride blocks.
    {
        int o = t & 31, grp = t >> 5;
        float s = 0.f;
        for (int b = grp; b < nblocks; b += 8) s += ws[(size_t)b * 32 + o];
        redA[grp][o] = s;
    }
    // Phase B: degrees 1..3. p = t>>5, 32 lanes per polynomial.
    {
        int p = t >> 5, li = t & 31;
        float s0 = 0.f, s1 = 0.f, s2 = 0.f, s3 = 0.f;
        for (int i = li; i < 512; i += 32) {
            float cv = c3[(p << 9) + i];
            int d1 = (i >> 6) & 7, d2 = (i >> 3) & 7, d3 = i & 7;
            s0 = fmaf(cv, xs[0][d1] * xs[0][d2] * xs[0][d3], s0);
            s1 = fmaf(cv, xs[1][d1] * xs[1][d2] * xs[1][d3], s1);
            s2 = fmaf(cv, xs[2][d1] * xs[2][d2] * xs[2][d3], s2);
            s3 = fmaf(cv, xs[3][d1] * xs[3][d2] * xs[3][d3], s3);
        }
        for (int i = li; i < 64; i += 32) {
            float cv = c2[(p << 6) + i];
            int d1 = (i >> 3) & 7, d2 = i & 7;
            s0 = fmaf(cv, xs[0][d1] * xs[0][d2], s0);
            s1 = fmaf(cv, xs[1][d1] * xs[1][d2], s1);
            s2 = fmaf(cv, xs[2][d1] * xs[2][d2], s2);
            s3 = fmaf(cv, xs[3][d1] * xs[3][d2], s3);
        }
        if (li < 8) {
            float cv = c1[(p << 3) + li];
            s0 = fmaf(cv, xs[0][li], s0);
            s1 = fmaf(cv, xs[1][li], s1);
            s2 = fmaf(cv, xs[2][li], s2);
            s3 = fmaf(cv, xs[3][li], s3);
        }
        redB[p][li][0] = s0; redB[p][li][1] = s1; redB[p][li][2] = s2; redB[p][li][3] = s3;
    }
    __syncthreads();
    if (t < 32) {
        int neu = t >> 3, p = t & 7;
        float tot = bias[p];
        #pragma unroll
        for (int grp = 0; grp < 8; ++grp) tot += redA[grp][t];
        for (int li = 0; li < 32; ++li) tot += redB[p][li][neu];
        out[t] = tot;
    }
}

extern "C" void kernel_launch(void* const* d_in, const int* in_sizes, int n_in,
                              void* d_out, int out_size, void* d_ws, size_t ws_size,
                              hipStream_t stream) {
    const float* X    = (const float*)d_in[0];
    const float* bias = (const float*)d_in[1];
    const float* c1   = (const float*)d_in[2];
    const float* c2   = (const float*)d_in[3];
    const float* c3   = (const float*)d_in[4];
    const float* c4   = (const float*)d_in[5];
    const float* c5   = (const float*)d_in[6];
    const float* c6   = (const float*)d_in[7];
    const float* c7   = (const float*)d_in[8];
    const float* c8   = (const float*)d_in[9];
    float* out = (float*)d_out;
    float* ws  = (float*)d_ws;

    int blocks = 1024;
    size_t maxb = ws_size / (32 * sizeof(float));
    if ((size_t)blocks > maxb) blocks = (int)maxb;
    if (blocks < 1) blocks = 1;

    poly_big<<<blocks, 512, 0, stream>>>(X, c4, c5, c6, c7, c8, ws);
    poly_final<<<1, 256, 0, stream>>>(X, bias, c1, c2, c3, ws, blocks, out);
}

// Round 5
// 396.131 us; speedup vs baseline: 2.0901x; 1.0080x over previous
//
#include <hip/hip_runtime.h>
#include <hip/hip_bf16.h>

// Segment enumeration: degrees 8,7,6,5,4 — each segment is 4096 contiguous
// floats of one polynomial row (16 KB). counts: 8*4096, 8*512, 8*64, 8*8, 8*1.
#define OFF7 32768
#define OFF6 36864
#define OFF5 37376
#define OFF4 37440
#define NSEG 37448

__device__ __forceinline__ float4 mul4(float4 a, float4 b) {
    return make_float4(a.x * b.x, a.y * b.y, a.z * b.z, a.w * b.w);
}
__device__ __forceinline__ float4 fma4s(float s, float4 b, float4 c) {
    return make_float4(fmaf(s, b.x, c.x), fmaf(s, b.y, c.y),
                       fmaf(s, b.z, c.z), fmaf(s, b.w, c.w));
}
__device__ __forceinline__ float4 fma44(float4 a, float4 b, float4 c) {
    return make_float4(fmaf(a.x, b.x, c.x), fmaf(a.y, b.y, c.y),
                       fmaf(a.z, b.z, c.z), fmaf(a.w, b.w, c.w));
}

struct SegInfo {
    const float4* base;  // per-lane pointer into the segment
    float4 th;           // per-segment high Kronecker factor (4 neurons)
    int p;               // polynomial row 0..7
};

// Plain by-value decode: no references, no lambda — keeps SROA trivial.
__device__ __forceinline__ SegInfo seg_decode(
    int g, int l,
    const float* c4, const float* c5, const float* c6,
    const float* c7, const float* c8,
    const float4* T1s, const float4* T2s)
{
    SegInfo si;
    const float* s;
    if (g < OFF7) {
        si.p = g >> 12; int hi = g & 4095;
        s = c8 + ((size_t)si.p << 24) + ((size_t)hi << 12);
        si.th = mul4(T2s[hi >> 6], T2s[hi & 63]);
    } else if (g < OFF6) {
        int t = g - OFF7; si.p = t >> 9; int hi = t & 511;
        s = c7 + ((size_t)si.p << 21) + ((size_t)hi << 12);
        si.th = mul4(T1s[hi >> 6], T2s[hi & 63]);
    } else if (g < OFF5) {
        int t = g - OFF6; si.p = t >> 6; int hi = t & 63;
        s = c6 + ((size_t)si.p << 18) + ((size_t)hi << 12);
        si.th = T2s[hi];
    } else if (g < OFF4) {
        int t = g - OFF5; si.p = t >> 3; int hi = t & 7;
        s = c5 + ((size_t)si.p << 15) + ((size_t)hi << 12);
        si.th = T1s[hi];
    } else {
        si.p = g - OFF4;
        s = c4 + ((size_t)si.p << 12);
        si.th = make_float4(1.f, 1.f, 1.f, 1.f);
    }
    si.base = (const float4*)s + l;
    return si;
}

// chunk k of a segment lives at base + k*64 float4s (1 KB per chunk per wave)
#define LOADA(si) { A0 = (si).base[0];   A1 = (si).base[64];  A2 = (si).base[128]; A3 = (si).base[192]; \
                    A4 = (si).base[256]; A5 = (si).base[320]; A6 = (si).base[384]; A7 = (si).base[448]; }
#define LOADB(si) { B0 = (si).base[512]; B1 = (si).base[576]; B2 = (si).base[640]; B3 = (si).base[704]; \
                    B4 = (si).base[768]; B5 = (si).base[832]; B6 = (si).base[896]; B7 = (si).base[960]; }
// one 64-float4 chunk: acc += T2[k*4+lhi] * (cv.x*tl0 + cv.y*tl1 + cv.z*tl2 + cv.w*tl3)
#define STEP(cv, kk) { const float4 th_ = T2s[((kk) << 2) + lhi]; \
    float4 inner = make_float4((cv).x * tl0.x, (cv).x * tl0.y, (cv).x * tl0.z, (cv).x * tl0.w); \
    inner = fma4s((cv).y, tl1, inner); \
    inner = fma4s((cv).z, tl2, inner); \
    inner = fma4s((cv).w, tl3, inner); \
    acc = fma44(th_, inner, acc); }

// Degrees 4..8. Identity: for element m = k*256 + l*4 + j of a 4096-float
// segment, kron^4[m] = T2[k*4 + (l>>4)] * T2[(l&15)*4 + j]. Low factor fixed
// per lane (registers), high factor is a broadcast LDS read. Grid-stride
// over segments; while computing segment g, the 16 loads of segment g+W are
// issued into the just-freed named registers (A half, then B half).
// amdgpu_waves_per_eu(4,4) pins the allocator to a 128-VGPR budget so the
// 16 in-flight float4s live in registers instead of spilling to scratch
// (r3/r4 showed the default heuristic targets 8 waves/EU = 64 VGPR + spills).
__global__ __attribute__((amdgpu_waves_per_eu(4, 4))) __launch_bounds__(512)
void poly_big(
    const float* __restrict__ X,
    const float* __restrict__ c4, const float* __restrict__ c5,
    const float* __restrict__ c6, const float* __restrict__ c7,
    const float* __restrict__ c8, float* __restrict__ ws)
{
    __shared__ float4 T1s[8], T2s[64];
    __shared__ float part[32];
    const int tid = threadIdx.x;

    if (tid < 8)  T1s[tid] = make_float4(X[tid], X[8 + tid], X[16 + tid], X[24 + tid]);
    if (tid < 32) part[tid] = 0.f;
    __syncthreads();
    if (tid < 64) T2s[tid] = mul4(T1s[tid >> 3], T1s[tid & 7]);
    __syncthreads();

    const int l = tid & 63;
    const int lhi = l >> 4;
    const float4 tl0 = T2s[((l & 15) << 2) + 0];
    const float4 tl1 = T2s[((l & 15) << 2) + 1];
    const float4 tl2 = T2s[((l & 15) << 2) + 2];
    const float4 tl3 = T2s[((l & 15) << 2) + 3];

    const int wid = (blockIdx.x * blockDim.x + tid) >> 6;
    const int W   = (gridDim.x * blockDim.x) >> 6;

    if (wid < NSEG) {
        SegInfo cur = seg_decode(wid, l, c4, c5, c6, c7, c8, T1s, T2s);
        float4 A0, A1, A2, A3, A4, A5, A6, A7;
        float4 B0, B1, B2, B3, B4, B5, B6, B7;
        LOADA(cur);
        LOADB(cur);

        for (int g = wid; g < NSEG; ) {
            const int gn = g + W;          // wave-uniform
            float4 acc = make_float4(0.f, 0.f, 0.f, 0.f);
            STEP(A0, 0) STEP(A1, 1) STEP(A2, 2) STEP(A3, 3)
            STEP(A4, 4) STEP(A5, 5) STEP(A6, 6) STEP(A7, 7)
            SegInfo nxt = cur;
            if (gn < NSEG) {
                nxt = seg_decode(gn, l, c4, c5, c6, c7, c8, T1s, T2s);
                LOADA(nxt);
            }
            STEP(B0, 8)  STEP(B1, 9)  STEP(B2, 10) STEP(B3, 11)
            STEP(B4, 12) STEP(B5, 13) STEP(B6, 14) STEP(B7, 15)
            if (gn < NSEG) {
                LOADB(nxt);
            }

            float vx = acc.x * cur.th.x, vy = acc.y * cur.th.y,
                  vz = acc.z * cur.th.z, vw = acc.w * cur.th.w;
            #pragma unroll
            for (int m = 32; m; m >>= 1) {
                vx += __shfl_xor(vx, m);
                vy += __shfl_xor(vy, m);
                vz += __shfl_xor(vz, m);
                vw += __shfl_xor(vw, m);
            }
            if (l == 0) {
                atomicAdd(&part[(cur.p << 2) + 0], vx);
                atomicAdd(&part[(cur.p << 2) + 1], vy);
                atomicAdd(&part[(cur.p << 2) + 2], vz);
                atomicAdd(&part[(cur.p << 2) + 3], vw);
            }
            cur = nxt;
            g = gn;
        }
    }
    __syncthreads();
    // ws layout: [block][o] with o = neu*8 + p  (matches output layout)
    if (tid < 32) ws[(size_t)blockIdx.x * 32 + tid] = part[((tid & 7) << 2) + (tid >> 3)];
}

// Finalize: reduce block partials + bias + degrees 1..3.
__global__ __launch_bounds__(256) void poly_final(
    const float* __restrict__ X, const float* __restrict__ bias,
    const float* __restrict__ c1, const float* __restrict__ c2,
    const float* __restrict__ c3, const float* __restrict__ ws,
    int nblocks, float* __restrict__ out)
{
    __shared__ float xs[4][8];
    __shared__ float redA[8][32];
    __shared__ float redB[8][32][4];
    const int t = threadIdx.x;
    if (t < 32) xs[t >> 3][t & 7] = X[t];
    __syncthreads();

    // Phase A: sum the big-kernel partials. o = neu*8+p, 8 groups stride blocks.
    {
        int o = t & 31, grp = t >> 5;
        float s = 0.f;
        for (int b = grp; b < nblocks; b += 8) s += ws[(size_t)b * 32 + o];
        redA[grp][o] = s;
    }
    // Phase B: degrees 1..3. p = t>>5, 32 lanes per polynomial.
    {
        int p = t >> 5, li = t & 31;
        float s0 = 0.f, s1 = 0.f, s2 = 0.f, s3 = 0.f;
        for (int i = li; i < 512; i += 32) {
            float cv = c3[(p << 9) + i];
            int d1 = (i >> 6) & 7, d2 = (i >> 3) & 7, d3 = i & 7;
            s0 = fmaf(cv, xs[0][d1] * xs[0][d2] * xs[0][d3], s0);
            s1 = fmaf(cv, xs[1][d1] * xs[1][d2] * xs[1][d3], s1);
            s2 = fmaf(cv, xs[2][d1] * xs[2][d2] * xs[2][d3], s2);
            s3 = fmaf(cv, xs[3][d1] * xs[3][d2] * xs[3][d3], s3);
        }
        for (int i = li; i < 64; i += 32) {
            float cv = c2[(p << 6) + i];
            int d1 = (i >> 3) & 7, d2 = i & 7;
            s0 = fmaf(cv, xs[0][d1] * xs[0][d2], s0);
            s1 = fmaf(cv, xs[1][d1] * xs[1][d2], s1);
            s2 = fmaf(cv, xs[2][d1] * xs[2][d2], s2);
            s3 = fmaf(cv, xs[3][d1] * xs[3][d2], s3);
        }
        if (li < 8) {
            float cv = c1[(p << 3) + li];
            s0 = fmaf(cv, xs[0][li], s0);
            s1 = fmaf(cv, xs[1][li], s1);
            s2 = fmaf(cv, xs[2][li], s2);
            s3 = fmaf(cv, xs[3][li], s3);
        }
        redB[p][li][0] = s0; redB[p][li][1] = s1; redB[p][li][2] = s2; redB[p][li][3] = s3;
    }
    __syncthreads();
    if (t < 32) {
        int neu = t >> 3, p = t & 7;
        float tot = bias[p];
        #pragma unroll
        for (int grp = 0; grp < 8; ++grp) tot += redA[grp][t];
        for (int li = 0; li < 32; ++li) tot += redB[p][li][neu];
        out[t] = tot;
    }
}

extern "C" void kernel_launch(void* const* d_in, const int* in_sizes, int n_in,
                              void* d_out, int out_size, void* d_ws, size_t ws_size,
                              hipStream_t stream) {
    const float* X    = (const float*)d_in[0];
    const float* bias = (const float*)d_in[1];
    const float* c1   = (const float*)d_in[2];
    const float* c2   = (const float*)d_in[3];
    const float* c3   = (const float*)d_in[4];
    const float* c4   = (const float*)d_in[5];
    const float* c5   = (const float*)d_in[6];
    const float* c6   = (const float*)d_in[7];
    const float* c7   = (const float*)d_in[8];
    const float* c8   = (const float*)d_in[9];
    float* out = (float*)d_out;
    float* ws  = (float*)d_ws;

    int blocks = 1024;
    size_t maxb = ws_size / (32 * sizeof(float));
    if ((size_t)blocks > maxb) blocks = (int)maxb;
    if (blocks < 1) blocks = 1;

    poly_big<<<blocks, 512, 0, stream>>>(X, c4, c5, c6, c7, c8, ws);
    poly_final<<<1, 256, 0, stream>>>(X, bias, c1, c2, c3, ws, blocks, out);
}

// Round 6
// 172.111 us; speedup vs baseline: 4.8105x; 2.3016x over previous
//
#include <hip/hip_runtime.h>
#include <hip/hip_bf16.h>
#include <stdint.h>

// Segment enumeration: degrees 8,7,6,5,4 — each segment is 4096 contiguous
// floats of one polynomial row (16 KB). counts: 8*4096, 8*512, 8*64, 8*8, 8*1.
#define OFF7 32768
#define OFF6 36864
#define OFF5 37376
#define OFF4 37440
#define NSEG 37448

typedef __attribute__((address_space(1))) const uint32_t g_u32;
typedef __attribute__((address_space(3))) uint32_t l_u32;

// async HBM->LDS DMA, 16B per lane; LDS dest = wave-uniform base + lane*16.
__device__ __forceinline__ void gload_lds16(const float* g, float* l) {
    __builtin_amdgcn_global_load_lds((g_u32*)g, (l_u32*)l, 16, 0, 0);
}

__device__ __forceinline__ float4 mul4(float4 a, float4 b) {
    return make_float4(a.x * b.x, a.y * b.y, a.z * b.z, a.w * b.w);
}
__device__ __forceinline__ float4 fma4s(float s, float4 b, float4 c) {
    return make_float4(fmaf(s, b.x, c.x), fmaf(s, b.y, c.y),
                       fmaf(s, b.z, c.z), fmaf(s, b.w, c.w));
}
__device__ __forceinline__ float4 fma44(float4 a, float4 b, float4 c) {
    return make_float4(fmaf(a.x, b.x, c.x), fmaf(a.y, b.y, c.y),
                       fmaf(a.z, b.z, c.z), fmaf(a.w, b.w, c.w));
}

struct SegInfo {
    const float* seg;  // segment base (4096 floats)
    float4 th;         // per-segment high Kronecker factor (4 neurons)
    int p;             // polynomial row 0..7
};

__device__ __forceinline__ SegInfo seg_decode(
    int g,
    const float* c4, const float* c5, const float* c6,
    const float* c7, const float* c8,
    const float4* T1s, const float4* T2s)
{
    SegInfo si;
    if (g < OFF7) {
        si.p = g >> 12; int hi = g & 4095;
        si.seg = c8 + ((size_t)si.p << 24) + ((size_t)hi << 12);
        si.th = mul4(T2s[hi >> 6], T2s[hi & 63]);
    } else if (g < OFF6) {
        int t = g - OFF7; si.p = t >> 9; int hi = t & 511;
        si.seg = c7 + ((size_t)si.p << 21) + ((size_t)hi << 12);
        si.th = mul4(T1s[hi >> 6], T2s[hi & 63]);
    } else if (g < OFF5) {
        int t = g - OFF6; si.p = t >> 6; int hi = t & 63;
        si.seg = c6 + ((size_t)si.p << 18) + ((size_t)hi << 12);
        si.th = T2s[hi];
    } else if (g < OFF4) {
        int t = g - OFF5; si.p = t >> 3; int hi = t & 7;
        si.seg = c5 + ((size_t)si.p << 15) + ((size_t)hi << 12);
        si.th = T1s[hi];
    } else {
        si.p = g - OFF4;
        si.seg = c4 + ((size_t)si.p << 12);
        si.th = make_float4(1.f, 1.f, 1.f, 1.f);
    }
    return si;
}

// wave stages its 4 chunks (1KB each) of a segment into buf[bi]
#define STAGE(bi, segptr) { \
    _Pragma("unroll") \
    for (int j_ = 0; j_ < 4; ++j_) { \
        const int c_ = (wave << 2) + j_; \
        gload_lds16((segptr) + (c_ << 8) + (lane << 2), &buf[bi][c_ << 8]); \
    } }

// Degrees 4..8. Identity: for float4 idx = q*256+tid of a segment,
// kron^4 = T2[(q*4 + tid/64)*4 + (tid&63)/16] * T2[(tid&15)*4 + j].
// HBM->LDS DMA double-buffer (zero VGPR staging cost), 2-phase recipe:
// STAGE next; compute cur; vmcnt(0); barrier; swap.
__global__ __launch_bounds__(256) void poly_big(
    const float* __restrict__ X,
    const float* __restrict__ c4, const float* __restrict__ c5,
    const float* __restrict__ c6, const float* __restrict__ c7,
    const float* __restrict__ c8, float* __restrict__ ws)
{
    __shared__ float4 T1s[8], T2s[64];
    __shared__ float part[32];
    __shared__ float buf[2][4096];
    const int tid = threadIdx.x;

    if (tid < 8)  T1s[tid] = make_float4(X[tid], X[8 + tid], X[16 + tid], X[24 + tid]);
    if (tid < 32) part[tid] = 0.f;
    __syncthreads();
    if (tid < 64) T2s[tid] = mul4(T1s[tid >> 3], T1s[tid & 7]);
    __syncthreads();

    const int wave = tid >> 6;
    const int lane = tid & 63;
    const int lhi  = (tid & 63) >> 4;
    const float4 tl0 = T2s[((tid & 15) << 2) + 0];
    const float4 tl1 = T2s[((tid & 15) << 2) + 1];
    const float4 tl2 = T2s[((tid & 15) << 2) + 2];
    const float4 tl3 = T2s[((tid & 15) << 2) + 3];

    const int nB = gridDim.x;
    int g    = (int)(((long long)blockIdx.x * NSEG) / nB);
    int gend = (int)(((long long)(blockIdx.x + 1) * NSEG) / nB);

    SegInfo cur = seg_decode(g, c4, c5, c6, c7, c8, T1s, T2s);
    int curp = cur.p;
    STAGE(0, cur.seg);
    asm volatile("s_waitcnt vmcnt(0)" ::: "memory");
    __syncthreads();

    float4 runacc = make_float4(0.f, 0.f, 0.f, 0.f);
    int bi = 0;
    for (;;) {
        const bool more = (g + 1) < gend;
        SegInfo nxt = cur;
        if (more) {
            nxt = seg_decode(g + 1, c4, c5, c6, c7, c8, T1s, T2s);
            STAGE(bi ^ 1, nxt.seg);
        }

        float4 acc = make_float4(0.f, 0.f, 0.f, 0.f);
        #pragma unroll
        for (int q = 0; q < 4; ++q) {
            const float4 cv = *(const float4*)&buf[bi][((q << 8) + tid) << 2];
            const float4 th = T2s[(q << 4) + ((tid >> 6) << 2) + lhi];
            float4 inner = make_float4(cv.x * tl0.x, cv.x * tl0.y,
                                       cv.x * tl0.z, cv.x * tl0.w);
            inner = fma4s(cv.y, tl1, inner);
            inner = fma4s(cv.z, tl2, inner);
            inner = fma4s(cv.w, tl3, inner);
            acc = fma44(th, inner, acc);
        }
        runacc = fma44(acc, cur.th, runacc);

        if (!more || nxt.p != curp) {   // block-uniform branch, rare
            float vx = runacc.x, vy = runacc.y, vz = runacc.z, vw = runacc.w;
            #pragma unroll
            for (int m = 32; m; m >>= 1) {
                vx += __shfl_xor(vx, m);
                vy += __shfl_xor(vy, m);
                vz += __shfl_xor(vz, m);
                vw += __shfl_xor(vw, m);
            }
            if (lane == 0) {
                atomicAdd(&part[(curp << 2) + 0], vx);
                atomicAdd(&part[(curp << 2) + 1], vy);
                atomicAdd(&part[(curp << 2) + 2], vz);
                atomicAdd(&part[(curp << 2) + 3], vw);
            }
            runacc = make_float4(0.f, 0.f, 0.f, 0.f);
            curp = nxt.p;
        }
        if (!more) break;
        asm volatile("s_waitcnt vmcnt(0)" ::: "memory");
        __syncthreads();
        bi ^= 1;
        cur = nxt;
        ++g;
    }
    __syncthreads();
    // ws layout: [block][o] with o = neu*8 + p  (matches output layout)
    if (tid < 32) ws[(size_t)blockIdx.x * 32 + tid] = part[((tid & 7) << 2) + (tid >> 3)];
}

// Finalize: reduce block partials + bias + degrees 1..3.
__global__ __launch_bounds__(256) void poly_final(
    const float* __restrict__ X, const float* __restrict__ bias,
    const float* __restrict__ c1, const float* __restrict__ c2,
    const float* __restrict__ c3, const float* __restrict__ ws,
    int nblocks, float* __restrict__ out)
{
    __shared__ float xs[4][8];
    __shared__ float redA[8][32];
    __shared__ float redB[8][32][4];
    const int t = threadIdx.x;
    if (t < 32) xs[t >> 3][t & 7] = X[t];
    __syncthreads();

    // Phase A: sum the big-kernel partials. o = neu*8+p, 8 groups stride blocks.
    {
        int o = t & 31, grp = t >> 5;
        float s = 0.f;
        for (int b = grp; b < nblocks; b += 8) s += ws[(size_t)b * 32 + o];
        redA[grp][o] = s;
    }
    // Phase B: degrees 1..3. p = t>>5, 32 lanes per polynomial.
    {
        int p = t >> 5, li = t & 31;
        float s0 = 0.f, s1 = 0.f, s2 = 0.f, s3 = 0.f;
        for (int i = li; i < 512; i += 32) {
            float cv = c3[(p << 9) + i];
            int d1 = (i >> 6) & 7, d2 = (i >> 3) & 7, d3 = i & 7;
            s0 = fmaf(cv, xs[0][d1] * xs[0][d2] * xs[0][d3], s0);
            s1 = fmaf(cv, xs[1][d1] * xs[1][d2] * xs[1][d3], s1);
            s2 = fmaf(cv, xs[2][d1] * xs[2][d2] * xs[2][d3], s2);
            s3 = fmaf(cv, xs[3][d1] * xs[3][d2] * xs[3][d3], s3);
        }
        for (int i = li; i < 64; i += 32) {
            float cv = c2[(p << 6) + i];
            int d1 = (i >> 3) & 7, d2 = i & 7;
            s0 = fmaf(cv, xs[0][d1] * xs[0][d2], s0);
            s1 = fmaf(cv, xs[1][d1] * xs[1][d2], s1);
            s2 = fmaf(cv, xs[2][d1] * xs[2][d2], s2);
            s3 = fmaf(cv, xs[3][d1] * xs[3][d2], s3);
        }
        if (li < 8) {
            float cv = c1[(p << 3) + li];
            s0 = fmaf(cv, xs[0][li], s0);
            s1 = fmaf(cv, xs[1][li], s1);
            s2 = fmaf(cv, xs[2][li], s2);
            s3 = fmaf(cv, xs[3][li], s3);
        }
        redB[p][li][0] = s0; redB[p][li][1] = s1; redB[p][li][2] = s2; redB[p][li][3] = s3;
    }
    __syncthreads();
    if (t < 32) {
        int neu = t >> 3, p = t & 7;
        float tot = bias[p];
        #pragma unroll
        for (int grp = 0; grp < 8; ++grp) tot += redA[grp][t];
        for (int li = 0; li < 32; ++li) tot += redB[p][li][neu];
        out[t] = tot;
    }
}

extern "C" void kernel_launch(void* const* d_in, const int* in_sizes, int n_in,
                              void* d_out, int out_size, void* d_ws, size_t ws_size,
                              hipStream_t stream) {
    const float* X    = (const float*)d_in[0];
    const float* bias = (const float*)d_in[1];
    const float* c1   = (const float*)d_in[2];
    const float* c2   = (const float*)d_in[3];
    const float* c3   = (const float*)d_in[4];
    const float* c4   = (const float*)d_in[5];
    const float* c5   = (const float*)d_in[6];
    const float* c6   = (const float*)d_in[7];
    const float* c7   = (const float*)d_in[8];
    const float* c8   = (const float*)d_in[9];
    float* out = (float*)d_out;
    float* ws  = (float*)d_ws;

    int blocks = 1280;
    size_t maxb = ws_size / (32 * sizeof(float));
    if ((size_t)blocks > maxb) blocks = (int)maxb;
    if (blocks < 1) blocks = 1;

    poly_big<<<blocks, 256, 0, stream>>>(X, c4, c5, c6, c7, c8, ws);
    poly_final<<<1, 256, 0, stream>>>(X, bias, c1, c2, c3, ws, blocks, out);
}

// Round 7
// 129.970 us; speedup vs baseline: 6.3703x; 1.3242x over previous
//
#include <hip/hip_runtime.h>
#include <hip/hip_bf16.h>
#include <stdint.h>

// Segment = 4096 contiguous floats (16 KB) of one polynomial row.
// Degrees 8,7,6,5,4 -> counts 8*4096, 8*512, 8*64, 8*8, 8*1 = 37448 segments.
// Work quantum = quarter-segment (4 chunks x 1KB = 4KB), NQ = NSEG*4.
#define OFF7 32768
#define OFF6 36864
#define OFF5 37376
#define OFF4 37440
#define NSEG 37448
#define NQ   (NSEG * 4)

typedef __attribute__((address_space(1))) const uint32_t g_u32;
typedef __attribute__((address_space(3))) uint32_t l_u32;

// async HBM->LDS DMA, 16B per lane; LDS dest = wave-uniform base + lane*16.
__device__ __forceinline__ void gload_lds16(const float* g, float* l) {
    __builtin_amdgcn_global_load_lds((g_u32*)g, (l_u32*)l, 16, 0, 0);
}

__device__ __forceinline__ float4 mul4(float4 a, float4 b) {
    return make_float4(a.x * b.x, a.y * b.y, a.z * b.z, a.w * b.w);
}
__device__ __forceinline__ float4 fma4s(float s, float4 b, float4 c) {
    return make_float4(fmaf(s, b.x, c.x), fmaf(s, b.y, c.y),
                       fmaf(s, b.z, c.z), fmaf(s, b.w, c.w));
}
__device__ __forceinline__ float4 fma44(float4 a, float4 b, float4 c) {
    return make_float4(fmaf(a.x, b.x, c.x), fmaf(a.y, b.y, c.y),
                       fmaf(a.z, b.z, c.z), fmaf(a.w, b.w, c.w));
}

struct SegInfo {
    const float* seg;  // segment base (4096 floats)
    float4 th;         // per-segment high Kronecker factor (4 neurons)
    int p;             // polynomial row 0..7
};

__device__ __forceinline__ SegInfo seg_decode(
    int g,
    const float* c4, const float* c5, const float* c6,
    const float* c7, const float* c8,
    const float4* T1s, const float4* T2s)
{
    SegInfo si;
    if (g < OFF7) {
        si.p = g >> 12; int hi = g & 4095;
        si.seg = c8 + ((size_t)si.p << 24) + ((size_t)hi << 12);
        si.th = mul4(T2s[hi >> 6], T2s[hi & 63]);
    } else if (g < OFF6) {
        int t = g - OFF7; si.p = t >> 9; int hi = t & 511;
        si.seg = c7 + ((size_t)si.p << 21) + ((size_t)hi << 12);
        si.th = mul4(T1s[hi >> 6], T2s[hi & 63]);
    } else if (g < OFF5) {
        int t = g - OFF6; si.p = t >> 6; int hi = t & 63;
        si.seg = c6 + ((size_t)si.p << 18) + ((size_t)hi << 12);
        si.th = T2s[hi];
    } else if (g < OFF4) {
        int t = g - OFF5; si.p = t >> 3; int hi = t & 7;
        si.seg = c5 + ((size_t)si.p << 15) + ((size_t)hi << 12);
        si.th = T1s[hi];
    } else {
        si.p = g - OFF4;
        si.seg = c4 + ((size_t)si.p << 12);
        si.th = make_float4(1.f, 1.f, 1.f, 1.f);
    }
    return si;
}

// Stage quantum (segment seg, quarter u) into this wave's private LDS half:
// chunk j (1KB) -> dst + j*256 floats. vmcnt += 4 per call.
#define STAGE(dst, segptr, u) { \
    _Pragma("unroll") \
    for (int j_ = 0; j_ < 4; ++j_) { \
        gload_lds16((segptr) + ((((u) << 2) + j_) << 8) + (lane << 2), \
                    (dst) + (j_ << 8)); \
    } }

// Barrier-free wave-private pipeline. Wave w owns buf[bi][w*1024 .. +1024)
// (2 x 4KB halves). Loop: STAGE next quantum into other half (4 DMA ops),
// s_waitcnt vmcnt(4) (previous quantum landed; next stays in flight),
// compute own half. No __syncthreads in the loop - waves self-pace.
// Identity per element m = c*256 + lane*4 + j of a segment (c = 4u+q):
// kron^4[m] = T2[c*4 + lane/16] * T2[(lane&15)*4 + j].
__global__ __launch_bounds__(256) void poly_big(
    const float* __restrict__ X,
    const float* __restrict__ c4, const float* __restrict__ c5,
    const float* __restrict__ c6, const float* __restrict__ c7,
    const float* __restrict__ c8, float* __restrict__ ws)
{
    __shared__ float4 T1s[8], T2s[64];
    __shared__ float part[32];
    __shared__ float buf[2][4096];
    const int tid = threadIdx.x;

    if (tid < 8)  T1s[tid] = make_float4(X[tid], X[8 + tid], X[16 + tid], X[24 + tid]);
    if (tid < 32) part[tid] = 0.f;
    __syncthreads();
    if (tid < 64) T2s[tid] = mul4(T1s[tid >> 3], T1s[tid & 7]);
    __syncthreads();

    const int wave = tid >> 6;
    const int lane = tid & 63;
    const int lhi  = lane >> 4;
    const float4 tl0 = T2s[((lane & 15) << 2) + 0];
    const float4 tl1 = T2s[((lane & 15) << 2) + 1];
    const float4 tl2 = T2s[((lane & 15) << 2) + 2];
    const float4 tl3 = T2s[((lane & 15) << 2) + 3];

    const int wg = (blockIdx.x << 2) + wave;     // global wave id
    const int NW = gridDim.x << 2;
    int Q    = (int)(((long long)wg * NQ) / NW);
    int Qend = (int)(((long long)(wg + 1) * NQ) / NW);

    if (Q < Qend) {
        float* h0 = &buf[0][wave << 10];
        float* h1 = &buf[1][wave << 10];
        float* cbuf = h0;
        float* nbuf = h1;

        SegInfo cur = seg_decode(Q >> 2, c4, c5, c6, c7, c8, T1s, T2s);
        int curu = Q & 3;
        int curp = cur.p;
        STAGE(cbuf, cur.seg, curu);

        float4 runacc = make_float4(0.f, 0.f, 0.f, 0.f);
        for (;;) {
            const bool more = (Q + 1) < Qend;
            SegInfo nxt = cur;
            int nxtu = curu;
            if (more) {
                nxtu = (Q + 1) & 3;
                nxt = seg_decode((Q + 1) >> 2, c4, c5, c6, c7, c8, T1s, T2s);
                STAGE(nbuf, nxt.seg, nxtu);
                asm volatile("s_waitcnt vmcnt(4)" ::: "memory");
            } else {
                asm volatile("s_waitcnt vmcnt(0)" ::: "memory");
            }

            float4 acc = make_float4(0.f, 0.f, 0.f, 0.f);
            #pragma unroll
            for (int q = 0; q < 4; ++q) {
                const float4 cv = *(const float4*)&cbuf[(q << 8) + (lane << 2)];
                const float4 th = T2s[(curu << 4) + (q << 2) + lhi];
                float4 inner = make_float4(cv.x * tl0.x, cv.x * tl0.y,
                                           cv.x * tl0.z, cv.x * tl0.w);
                inner = fma4s(cv.y, tl1, inner);
                inner = fma4s(cv.z, tl2, inner);
                inner = fma4s(cv.w, tl3, inner);
                acc = fma44(th, inner, acc);
            }
            runacc = fma44(acc, cur.th, runacc);

            if (!more || nxt.p != curp) {   // wave-uniform, rare
                float vx = runacc.x, vy = runacc.y, vz = runacc.z, vw = runacc.w;
                #pragma unroll
                for (int m = 32; m; m >>= 1) {
                    vx += __shfl_xor(vx, m);
                    vy += __shfl_xor(vy, m);
                    vz += __shfl_xor(vz, m);
                    vw += __shfl_xor(vw, m);
                }
                if (lane == 0) {
                    atomicAdd(&part[(curp << 2) + 0], vx);
                    atomicAdd(&part[(curp << 2) + 1], vy);
                    atomicAdd(&part[(curp << 2) + 2], vz);
                    atomicAdd(&part[(curp << 2) + 3], vw);
                }
                runacc = make_float4(0.f, 0.f, 0.f, 0.f);
                curp = nxt.p;
            }
            if (!more) break;
            cur = nxt; curu = nxtu; ++Q;
            float* t_ = cbuf; cbuf = nbuf; nbuf = t_;
        }
    }
    __syncthreads();
    // ws layout: [block][o] with o = neu*8 + p  (matches output layout)
    if (tid < 32) ws[(size_t)blockIdx.x * 32 + tid] = part[((tid & 7) << 2) + (tid >> 3)];
}

// Finalize: reduce block partials (1024 threads wide) + bias + degrees 1..3.
__global__ __launch_bounds__(1024) void poly_final(
    const float* __restrict__ X, const float* __restrict__ bias,
    const float* __restrict__ c1, const float* __restrict__ c2,
    const float* __restrict__ c3, const float* __restrict__ ws,
    int nblocks, float* __restrict__ out)
{
    __shared__ float xs[4][8];
    __shared__ float redA[32][32];
    __shared__ float redB[8][32][4];
    const int t = threadIdx.x;
    if (t < 32) xs[t >> 3][t & 7] = X[t];
    __syncthreads();

    // Phase A: sum big-kernel partials. o = neu*8+p; 32 groups stride blocks.
    {
        int o = t & 31, grp = t >> 5;
        float s = 0.f;
        for (int b = grp; b < nblocks; b += 32) s += ws[(size_t)b * 32 + o];
        redA[grp][o] = s;
    }
    // Phase B: degrees 1..3 on threads 0..255. p = t>>5, 32 lanes per poly.
    if (t < 256) {
        int p = t >> 5, li = t & 31;
        float s0 = 0.f, s1 = 0.f, s2 = 0.f, s3 = 0.f;
        for (int i = li; i < 512; i += 32) {
            float cv = c3[(p << 9) + i];
            int d1 = (i >> 6) & 7, d2 = (i >> 3) & 7, d3 = i & 7;
            s0 = fmaf(cv, xs[0][d1] * xs[0][d2] * xs[0][d3], s0);
            s1 = fmaf(cv, xs[1][d1] * xs[1][d2] * xs[1][d3], s1);
            s2 = fmaf(cv, xs[2][d1] * xs[2][d2] * xs[2][d3], s2);
            s3 = fmaf(cv, xs[3][d1] * xs[3][d2] * xs[3][d3], s3);
        }
        for (int i = li; i < 64; i += 32) {
            float cv = c2[(p << 6) + i];
            int d1 = (i >> 3) & 7, d2 = i & 7;
            s0 = fmaf(cv, xs[0][d1] * xs[0][d2], s0);
            s1 = fmaf(cv, xs[1][d1] * xs[1][d2], s1);
            s2 = fmaf(cv, xs[2][d1] * xs[2][d2], s2);
            s3 = fmaf(cv, xs[3][d1] * xs[3][d2], s3);
        }
        if (li < 8) {
            float cv = c1[(p << 3) + li];
            s0 = fmaf(cv, xs[0][li], s0);
            s1 = fmaf(cv, xs[1][li], s1);
            s2 = fmaf(cv, xs[2][li], s2);
            s3 = fmaf(cv, xs[3][li], s3);
        }
        redB[p][li][0] = s0; redB[p][li][1] = s1; redB[p][li][2] = s2; redB[p][li][3] = s3;
    }
    __syncthreads();
    if (t < 32) {
        int neu = t >> 3, p = t & 7;
        float tot = bias[p];
        #pragma unroll
        for (int grp = 0; grp < 32; ++grp) tot += redA[grp][t];
        for (int li = 0; li < 32; ++li) tot += redB[p][li][neu];
        out[t] = tot;
    }
}

extern "C" void kernel_launch(void* const* d_in, const int* in_sizes, int n_in,
                              void* d_out, int out_size, void* d_ws, size_t ws_size,
                              hipStream_t stream) {
    const float* X    = (const float*)d_in[0];
    const float* bias = (const float*)d_in[1];
    const float* c1   = (const float*)d_in[2];
    const float* c2   = (const float*)d_in[3];
    const float* c3   = (const float*)d_in[4];
    const float* c4   = (const float*)d_in[5];
    const float* c5   = (const float*)d_in[6];
    const float* c6   = (const float*)d_in[7];
    const float* c7   = (const float*)d_in[8];
    const float* c8   = (const float*)d_in[9];
    float* out = (float*)d_out;
    float* ws  = (float*)d_ws;

    // exactly 4 blocks/CU x 256 CUs resident (LDS-capped at ~33.4KB/block):
    // all blocks run from t=0, no dispatch tail.
    int blocks = 1024;
    size_t maxb = ws_size / (32 * sizeof(float));
    if ((size_t)blocks > maxb) blocks = (int)maxb;
    if (blocks < 1) blocks = 1;

    poly_big<<<blocks, 256, 0, stream>>>(X, c4, c5, c6, c7, c8, ws);
    poly_final<<<1, 1024, 0, stream>>>(X, bias, c1, c2, c3, ws, blocks, out);
}